// Round 8
// baseline (351.674 us; speedup 1.0000x reference)
//
#include <hip/hip_runtime.h>
#include <hip/hip_bf16.h>
#include <cstddef>
#include <cstdint>

typedef __attribute__((ext_vector_type(4))) __bf16 bf16x4;
typedef __attribute__((ext_vector_type(8))) __bf16 bf16x8;
typedef __attribute__((ext_vector_type(4))) float f32x4;

#define L_SEQ 2048
#define KD 768
#define N_HEAD 12
#define NB 4
#define NX 8192          // B*L
#define NALL 49152       // B*L*(1+5)
#define KVLD 1536        // merged K|V output row length

#define FENCE asm volatile("" ::: "memory")
#define BARRIER do { FENCE; __builtin_amdgcn_s_barrier(); FENCE; } while (0)

__device__ __forceinline__ void gload16(const __bf16* g, __bf16* l) {
    __builtin_amdgcn_global_load_lds(
        (const __attribute__((address_space(1))) void*)g,
        (__attribute__((address_space(3))) void*)l, 16, 0, 0);
}

// ---------------- weight fp32 -> bf16 ----------------
__global__ __launch_bounds__(256) void wconv_kernel(
    const float* __restrict__ W0, const float* __restrict__ W1,
    const float* __restrict__ W2, const float* __restrict__ W3,
    __bf16* __restrict__ O0, __bf16* __restrict__ O1,
    __bf16* __restrict__ O2, __bf16* __restrict__ O3)
{
    const float* src; __bf16* dst;
    switch (blockIdx.y) {
        case 0: src = W0; dst = O0; break;
        case 1: src = W1; dst = O1; break;
        case 2: src = W2; dst = O2; break;
        default: src = W3; dst = O3; break;
    }
    const int i = (blockIdx.x * 256 + threadIdx.x) * 4;
    const float4 v = *(const float4*)(src + i);
    bf16x4 t;
    t[0] = (__bf16)v.x; t[1] = (__bf16)v.y; t[2] = (__bf16)v.z; t[3] = (__bf16)v.w;
    *(bf16x4*)(dst + i) = t;
}

// ------------- convert+transpose into XT[n'(49152)][768] -------------
__global__ __launch_bounds__(256) void xconv_kernel(
    const float* __restrict__ x, const float* __restrict__ ax,
    __bf16* __restrict__ XT)
{
    __shared__ __bf16 S[64][72];
    const int t = threadIdx.x;
    const int ap = blockIdx.x >> 7;
    const int inner = blockIdx.x & 127;
    const int bb = inner >> 5;
    const int l0 = (inner & 31) * 64;
    const int d0 = blockIdx.y * 64;
    const int r = t >> 4;
    const int c4 = (t & 15) * 4;
    #pragma unroll
    for (int p = 0; p < 4; ++p) {
        const int d = d0 + r + p * 16;
        const float* src = (ap == 0)
            ? x + ((size_t)(bb * KD + d)) * L_SEQ
            : ax + (((size_t)(bb * KD + d)) * 5 + (ap - 1)) * L_SEQ;
        const float4 v = *(const float4*)(src + l0 + c4);
        S[c4 + 0][r + p * 16] = (__bf16)v.x;
        S[c4 + 1][r + p * 16] = (__bf16)v.y;
        S[c4 + 2][r + p * 16] = (__bf16)v.z;
        S[c4 + 3][r + p * 16] = (__bf16)v.w;
    }
    __syncthreads();
    #pragma unroll
    for (int p = 0; p < 4; ++p) {
        const int lr = r + p * 16;
        const bf16x4 v = *(const bf16x4*)&S[lr][c4];
        *(bf16x4*)(XT + ((size_t)ap * NX + bb * L_SEQ + l0 + lr) * KD + d0 + c4) = v;
    }
}

// ---------------- 128x256 occupancy-first GEMM (BK=32, 2 blocks/CU) ----------------
// Out = A[M][768] * Bt[N][768]^T + bias. 8 waves (2M x 4N), per-wave 64x64 (acc[4][4]).
// LDS: 2-ring x (A 128x32 = 8KB + B 256x32 = 16KB) = 48 KiB -> 2 blocks/CU.
// __launch_bounds__(512,4): cap regs at 128 -> 16 waves/CU. TLP (2 independent
// barrier domains per CU) hides LDS latency + barrier skew (m114/m97 mechanism).
// Step t: { BARRIER(buf t published); ds_read 8xb128; stage(t+1)->buf^1;
//           lgkm(0)+sched_barrier; 16 MFMA; vmcnt(0); }  (single barrier/step,
// ledger: reads of buf t retired pre-barrier; stage targets other buffer; stage
// drained pre-barrier so next step's reads see it.)
// Swizzle pair (verified R4, conflicts 10x down): stage k-slot (lane&3)^((lane>>3)&3),
// read slot kslc^((lr>>1)&3).
template <int MODE, int NM>   // MODE 0: bf16 OutT[n'][ldo]; MODE 1: fp32 out[(b*768+m)*2048+l]
__global__ __launch_bounds__(512, 4) void gemm128_kernel(
    const __bf16* __restrict__ A, const __bf16* __restrict__ Bt,
    const float* __restrict__ bias_lo, const float* __restrict__ bias_hi,
    void* __restrict__ Out, int ldo)
{
    __shared__ __bf16 SL[24576];   // 2 x 12288 (A 4096 + B 8192)
    // XCD-grouped swizzle: m-fast within an XCD's contiguous gidx range
    const int nwg8 = gridDim.x >> 3;
    const int gidx = (blockIdx.x & 7) * nwg8 + (blockIdx.x >> 3);
    const int m0 = (gidx % NM) * 128;
    const int n0 = (gidx / NM) * 256;

    const int tid = threadIdx.x;
    const int lane = tid & 63, wv = tid >> 6;
    const int wm = wv >> 2, wn = wv & 3;
    const int lr = lane & 15;
    const int kslc = lane >> 4;
    const int slotp = kslc ^ ((lr >> 1) & 3);
    const int srow = lane >> 2;
    const int skoff = ((lane & 3) ^ ((lane >> 3) & 3)) * 8;

    f32x4 acc[4][4];
    #pragma unroll
    for (int i = 0; i < 4; ++i)
        #pragma unroll
        for (int j = 0; j < 4; ++j)
            acc[i][j] = (f32x4){0.f, 0.f, 0.f, 0.f};

    const __bf16* gA = A + (size_t)m0 * KD + skoff + (size_t)srow * KD;
    const __bf16* gB = Bt + (size_t)n0 * KD + skoff + (size_t)srow * KD;

    // stage: A has 8 16-row chunks (1/wave), B has 16 (2/wave). 3 gloads/wave.
    auto STAGE = [&](int t) {
        __bf16* dst = SL + (t & 1) * 12288;
        gload16(gA + (size_t)(wv * 16) * KD + t * 32, dst + wv * 512);
        #pragma unroll
        for (int i2 = 0; i2 < 2; ++i2) {
            const int c = wv + i2 * 8;
            gload16(gB + (size_t)(c * 16) * KD + t * 32, dst + 4096 + c * 512);
        }
    };

    const int offA = (wm * 64 + lr) * 32 + slotp * 8;
    const int offB = 4096 + (wn * 64 + lr) * 32 + slotp * 8;

    STAGE(0);
    asm volatile("s_waitcnt vmcnt(0)" ::: "memory");

    #pragma unroll 4
    for (int t = 0; t < 24; ++t) {
        BARRIER;                       // buf t published (and prior reads retired)
        const __bf16* buf = SL + (t & 1) * 12288;
        bf16x8 af[4], bf_[4];
        #pragma unroll
        for (int i = 0; i < 4; ++i) af[i] = *(const bf16x8*)(buf + offA + i * 512);
        #pragma unroll
        for (int j = 0; j < 4; ++j) bf_[j] = *(const bf16x8*)(buf + offB + j * 512);
        if (t + 1 < 24) STAGE(t + 1);
        asm volatile("s_waitcnt lgkmcnt(0)" ::: "memory");
        __builtin_amdgcn_sched_barrier(0);
        __builtin_amdgcn_s_setprio(1);
        #pragma unroll
        for (int i = 0; i < 4; ++i)
            #pragma unroll
            for (int j = 0; j < 4; ++j)
                acc[i][j] = __builtin_amdgcn_mfma_f32_16x16x32_bf16(af[i], bf_[j], acc[i][j], 0, 0, 0);
        __builtin_amdgcn_s_setprio(0);
        asm volatile("s_waitcnt vmcnt(0)" ::: "memory");   // stage(t+1) landed
    }

    const int row0 = kslc * 4;   // C/D: col=lane&15 (n), row=(lane>>4)*4+reg (m)
    if (MODE == 0) {
        __bf16* T = SL + wv * 1152;          // 16 n-rows x 72 (64 m + pad)
        #pragma unroll
        for (int j = 0; j < 4; ++j) {
            __syncthreads();
            #pragma unroll
            for (int i = 0; i < 4; ++i) {
                bf16x4 v;
                #pragma unroll
                for (int r = 0; r < 4; ++r) {
                    const int mg = m0 + wm * 64 + i * 16 + row0 + r;
                    const float bb = (m0 < 768) ? bias_lo[mg] : bias_hi[mg - 768];
                    v[r] = (__bf16)(acc[i][j][r] + bb);
                }
                *(bf16x4*)(T + lr * 72 + i * 16 + row0) = v;
            }
            __syncthreads();
            const int rr = lane >> 2, seg = lane & 3;
            __bf16* dst = (__bf16*)Out + (size_t)(n0 + wn * 64 + j * 16 + rr) * ldo
                          + m0 + wm * 64 + seg * 16;
            const __bf16* src = T + rr * 72 + seg * 16;
            *(bf16x8*)dst = *(const bf16x8*)src;
            *(bf16x8*)(dst + 8) = *(const bf16x8*)(src + 8);
        }
    } else {
        const int b_ = n0 >> 11;
        const int l0 = (n0 & 2047) + wn * 64;
        float* o = (float*)Out;
        #pragma unroll
        for (int i = 0; i < 4; ++i)
            #pragma unroll
            for (int r = 0; r < 4; ++r) {
                const int mg = m0 + wm * 64 + i * 16 + row0 + r;
                const float bb = bias_lo[mg];
                #pragma unroll
                for (int j = 0; j < 4; ++j)
                    o[((size_t)(b_ * KD + mg)) * L_SEQ + l0 + j * 16 + lr] = acc[i][j][r] + bb;
            }
    }
}

// ---------------- attention (transposed, 16B loads) ----------------
// Qt: [8192][768]; KVt: [49152][1536] (K at +0, V at +768); attT: [8192][768]
__global__ __launch_bounds__(256) void attn_kernel(
    const __bf16* __restrict__ Qt, const __bf16* __restrict__ KVt,
    __bf16* __restrict__ attT)
{
    const int bid = blockIdx.x;
    const int lt = bid & 63;
    const int h = bid >> 6;
    const int tid = threadIdx.x;
    const int wave = tid >> 6, lane = tid & 63;
    const int half = lane >> 5, ln = lane & 31;
    const int n = lt * 128 + wave * 32 + ln;
    const int l = n & (L_SEQ - 1);
    const int c0 = h * 64 + half * 32;

    float q[32];
    {
        const __bf16* qp = Qt + (size_t)n * KD + c0;
        #pragma unroll
        for (int s = 0; s < 4; ++s) {
            const bf16x8 v = *(const bf16x8*)(qp + s * 8);
            #pragma unroll
            for (int j = 0; j < 8; ++j) q[s * 8 + j] = (float)v[j];
        }
    }

    float sc[10];
    #pragma unroll
    for (int w = 0; w < 5; ++w) {
        const int lw = l + w - 2;
        float acc = 0.f;
        if ((unsigned)lw < L_SEQ) {
            const __bf16* kp = KVt + (size_t)(n + w - 2) * KVLD + c0;
            #pragma unroll
            for (int s = 0; s < 4; ++s) {
                const bf16x8 v = *(const bf16x8*)(kp + s * 8);
                #pragma unroll
                for (int j = 0; j < 8; ++j) acc += q[s * 8 + j] * (float)v[j];
            }
        }
        sc[w] = acc;
    }
    #pragma unroll
    for (int a = 0; a < 5; ++a) {
        const __bf16* kp = KVt + ((size_t)(a + 1) * NX + n) * KVLD + c0;
        float acc = 0.f;
        #pragma unroll
        for (int s = 0; s < 4; ++s) {
            const bf16x8 v = *(const bf16x8*)(kp + s * 8);
            #pragma unroll
            for (int j = 0; j < 8; ++j) acc += q[s * 8 + j] * (float)v[j];
        }
        sc[5 + a] = acc;
    }

    #pragma unroll
    for (int i = 0; i < 10; ++i) {
        sc[i] += __shfl_xor(sc[i], 32);
        sc[i] *= 0.125f;
    }

    float mx = sc[0];
    #pragma unroll
    for (int i = 1; i < 10; ++i) mx = fmaxf(mx, sc[i]);
    float e[10], sum = 0.f;
    #pragma unroll
    for (int i = 0; i < 10; ++i) { e[i] = __expf(sc[i] - mx); sum += e[i]; }
    const float inv = 1.f / sum;

    float o[32];
    #pragma unroll
    for (int i = 0; i < 32; ++i) o[i] = 0.f;

    #pragma unroll
    for (int w = 0; w < 5; ++w) {
        const int lw = l + w - 2;
        if ((unsigned)lw < L_SEQ) {
            const __bf16* vp = KVt + (size_t)(n + w - 2) * KVLD + 768 + c0;
            #pragma unroll
            for (int s = 0; s < 4; ++s) {
                const bf16x8 v = *(const bf16x8*)(vp + s * 8);
                #pragma unroll
                for (int j = 0; j < 8; ++j) o[s * 8 + j] += e[w] * (float)v[j];
            }
        }
    }
    #pragma unroll
    for (int a = 0; a < 5; ++a) {
        const __bf16* vp = KVt + ((size_t)(a + 1) * NX + n) * KVLD + 768 + c0;
        #pragma unroll
        for (int s = 0; s < 4; ++s) {
            const bf16x8 v = *(const bf16x8*)(vp + s * 8);
            #pragma unroll
            for (int j = 0; j < 8; ++j) o[s * 8 + j] += e[5 + a] * (float)v[j];
        }
    }

    __bf16* dst = attT + (size_t)n * KD + c0;
    #pragma unroll
    for (int s = 0; s < 4; ++s) {
        bf16x8 t;
        #pragma unroll
        for (int j = 0; j < 8; ++j) t[j] = (__bf16)(o[s * 8 + j] * inv);
        *(bf16x8*)(dst + s * 8) = t;
    }
}

extern "C" void kernel_launch(void* const* d_in, const int* in_sizes, int n_in,
                              void* d_out, int out_size, void* d_ws, size_t ws_size,
                              hipStream_t stream)
{
    const float* x  = (const float*)d_in[0];
    const float* ax = (const float*)d_in[1];
    const float* Wq = (const float*)d_in[2];
    const float* bq = (const float*)d_in[3];
    const float* Wk = (const float*)d_in[4];
    const float* bk = (const float*)d_in[5];
    const float* Wv = (const float*)d_in[6];
    const float* bv = (const float*)d_in[7];
    const float* Wo = (const float*)d_in[8];
    const float* bo = (const float*)d_in[9];
    float* out = (float*)d_out;

    __bf16* p = (__bf16*)d_ws;
    __bf16* Wq_bf = p; p += 589824;
    __bf16* Wkv_bf = p;                       // [Wk_bf; Wv_bf] contiguous
    __bf16* Wk_bf = p; p += 589824;
    __bf16* Wv_bf = p; p += 589824;
    __bf16* Wo_bf = p; p += 589824;
    __bf16* Qt    = p; p += (size_t)KD * NX;
    __bf16* KVt   = p; p += (size_t)KVLD * NALL;
    __bf16* XT    = p; p += (size_t)KD * NALL;
    __bf16* attT  = p;

    wconv_kernel<<<dim3(576, 4), dim3(256), 0, stream>>>(Wq, Wk, Wv, Wo, Wq_bf, Wk_bf, Wv_bf, Wo_bf);
    xconv_kernel<<<dim3(768, 12), dim3(256), 0, stream>>>(x, ax, XT);

    // KV: M=1536 (12 m-blocks), N=49152 (192 n-blocks) -> 2304 blocks
    gemm128_kernel<0, 12><<<dim3(2304), dim3(512), 0, stream>>>(Wkv_bf, XT, bk, bv, KVt, KVLD);
    // Q: M=768 (6), N=8192 (32) -> 192 blocks
    gemm128_kernel<0, 6><<<dim3(192), dim3(512), 0, stream>>>(Wq_bf, XT, bq, bq, Qt, KD);

    attn_kernel<<<dim3(64 * N_HEAD), dim3(256), 0, stream>>>(Qt, KVt, attT);

    gemm128_kernel<1, 6><<<dim3(192), dim3(512), 0, stream>>>(Wo_bf, attT, bo, bo, out, 0);
}